// Round 11
// baseline (28386.911 us; speedup 1.0000x reference)
//
#include <hip/hip_runtime.h>
#include <hip/hip_bf16.h>

// Problem constants (B,T,D,L) = (16, 4096, 256, 512)
#define RNN_B 16
#define RNN_T 4096
#define RNN_D 256
#define RNN_L 512

typedef __fp16   fp16x2 __attribute__((ext_vector_type(2)));  // builtin-compatible
typedef _Float16 f16x8  __attribute__((ext_vector_type(8)));  // MFMA fragment
typedef float    f32x4  __attribute__((ext_vector_type(4)));

__device__ __forceinline__ unsigned pk2(float a, float b) {
    auto h = __builtin_amdgcn_cvt_pkrtz(a, b);   // __fp16 ext_vector(2)
    return __builtin_bit_cast(unsigned, h);
}

__device__ __forceinline__ uint4 pk4(float4 a, float4 b) {
    uint4 u;
    u.x = pk2(a.x, a.y); u.y = pk2(a.z, a.w);
    u.z = pk2(b.x, b.y); u.w = pk2(b.z, b.w);
    return u;
}

__device__ __forceinline__ float dot2u(unsigned wa, unsigned hb, float c) {
#if defined(__has_builtin) && __has_builtin(__builtin_amdgcn_fdot2)
    return __builtin_amdgcn_fdot2(__builtin_bit_cast(fp16x2, wa),
                                  __builtin_bit_cast(fp16x2, hb), c, false);
#else
    fp16x2 a = __builtin_bit_cast(fp16x2, wa), b = __builtin_bit_cast(fp16x2, hb);
    return c + (float)a[0] * (float)b[0] + (float)a[1] * (float)b[1];
#endif
}

// ---------------------------------------------------------------------------
// K1: Z[t,b,l] = sum_k x[b,t,k] * Wi[l,k] + bm[l] (f32 into hidden region).
// ---------------------------------------------------------------------------
__global__ __launch_bounds__(256) void proj_kernel(
        const float* __restrict__ x, const float* __restrict__ Wi,
        const float* __restrict__ bm, float* __restrict__ Zout) {
    __shared__ __align__(16) _Float16 As[64 * 40];
    __shared__ __align__(16) _Float16 Bs[64 * 40];

    const int bid = blockIdx.x;
    const int mt = bid >> 3, nt = bid & 7;
    const int mBase = mt * 64, nBase = nt * 64;
    const int tid = threadIdx.x;
    const int w = tid >> 6, l = tid & 63;

    const int srow = tid >> 2, skc = (tid & 3) * 8;
    const int m = mBase + srow;
    const int bb = m & 15, tt = m >> 4;
    const float* ax = x + ((size_t)bb * RNN_T + tt) * RNN_D + skc;
    const float* bw = Wi + (size_t)(nBase + srow) * RNN_D + skc;

    f32x4 acc[4] = {};

#pragma unroll 1
    for (int k0 = 0; k0 < RNN_D; k0 += 32) {
        __syncthreads();
        float4 a0 = *(const float4*)(ax + k0);
        float4 a1 = *(const float4*)(ax + k0 + 4);
        float4 b0 = *(const float4*)(bw + k0);
        float4 b1 = *(const float4*)(bw + k0 + 4);
        uint4 ua = {pk2(a0.x, a0.y), pk2(a0.z, a0.w), pk2(a1.x, a1.y), pk2(a1.z, a1.w)};
        uint4 ub = {pk2(b0.x, b0.y), pk2(b0.z, b0.w), pk2(b1.x, b1.y), pk2(b1.z, b1.w)};
        *(uint4*)(As + srow * 40 + skc) = ua;
        *(uint4*)(Bs + srow * 40 + skc) = ub;
        __syncthreads();

        f16x8 af = *(const f16x8*)(As + (w * 16 + (l & 15)) * 40 + (l >> 4) * 8);
#pragma unroll
        for (int n = 0; n < 4; ++n) {
            f16x8 bf = *(const f16x8*)(Bs + (n * 16 + (l & 15)) * 40 + (l >> 4) * 8);
            acc[n] = __builtin_amdgcn_mfma_f32_16x16x32_f16(af, bf, acc[n], 0, 0, 0);
        }
    }

    const int colL = l & 15, rg = l >> 4;
#pragma unroll
    for (int n = 0; n < 4; ++n) {
        const int col = nBase + n * 16 + colL;
        const float bias = bm[col];
#pragma unroll
        for (int q = 0; q < 4; ++q) {
            const int row = mBase + w * 16 + rg * 4 + q;
            Zout[(size_t)row * RNN_L + col] = acc[n][q] + bias;
        }
    }
}

// ---------------------------------------------------------------------------
// K2: sequential scan. 16 blocks (1/batch), 512 thr (8 waves), k-split.
// R7/R10: per-step VMEM weights fatal (latency).  R4-R6: arch-V capped 128.
// R8 insight reused here: wave w's phase-2 channels [64w,64w+64) ARE the
// h-slice wave w consumes in phase 1 -> h never touches LDS:
//   * h lives as 32 wave-uniform SGPRs (readlane after sigmoid).
//   * ALL weights register-resident: ch 0-5 pinned "+a" (192 u32 in AGPR,
//     VALU reads AGPR directly on unified-file gfx950), ch 6-7 + temps in V
//     (~124 u32, fits the stubborn 128-V cap -> NO scratch, NO LDS weights).
//   * LDS holds ONLY the cross-wave partial matrix, double-buffered ->
//     ONE barrier per step.
//   * z prefetched 1 step ahead; h-store fire-and-forget after barrier.
// ---------------------------------------------------------------------------
#define PARTSZ (8 * 8 * 65)          // floats per buffer, padded

#define DECL8(c) uint4 W##c##_0, W##c##_1, W##c##_2, W##c##_3, \
                       W##c##_4, W##c##_5, W##c##_6, W##c##_7
#define LOAD8(c) do { \
    const float4* p_ = (const float4*)(Wm + (size_t)(8 * l + (c)) * RNN_L + 64 * w); \
    W##c##_0 = pk4(p_[0], p_[1]);   W##c##_1 = pk4(p_[2], p_[3]); \
    W##c##_2 = pk4(p_[4], p_[5]);   W##c##_3 = pk4(p_[6], p_[7]); \
    W##c##_4 = pk4(p_[8], p_[9]);   W##c##_5 = pk4(p_[10], p_[11]); \
    W##c##_6 = pk4(p_[12], p_[13]); W##c##_7 = pk4(p_[14], p_[15]); } while (0)
#define PINA2(A, B) asm volatile("" : "+a"((A).x), "+a"((A).y), "+a"((A).z), "+a"((A).w), \
                                       "+a"((B).x), "+a"((B).y), "+a"((B).z), "+a"((B).w))
#define PINA8(c) do { PINA2(W##c##_0, W##c##_1); PINA2(W##c##_2, W##c##_3); \
                      PINA2(W##c##_4, W##c##_5); PINA2(W##c##_6, W##c##_7); } while (0)
#define DOT1(W, h0_, h1_, h2_, h3_, A) do { \
    A = dot2u((W).x, h0_, A); A = dot2u((W).y, h1_, A); \
    A = dot2u((W).z, h2_, A); A = dot2u((W).w, h3_, A); } while (0)
#define DOTC(c) do { \
    DOT1(W##c##_0, hp0,  hp1,  hp2,  hp3,  acc##c); \
    DOT1(W##c##_1, hp4,  hp5,  hp6,  hp7,  acc##c); \
    DOT1(W##c##_2, hp8,  hp9,  hp10, hp11, acc##c); \
    DOT1(W##c##_3, hp12, hp13, hp14, hp15, acc##c); \
    DOT1(W##c##_4, hp16, hp17, hp18, hp19, acc##c); \
    DOT1(W##c##_5, hp20, hp21, hp22, hp23, acc##c); \
    DOT1(W##c##_6, hp24, hp25, hp26, hp27, acc##c); \
    DOT1(W##c##_7, hp28, hp29, hp30, hp31, acc##c); } while (0)
#define RL(i) hp##i = __builtin_amdgcn_readlane(pkh, 2 * i)

__global__ void
__attribute__((amdgpu_flat_work_group_size(512, 512)))
__attribute__((amdgpu_waves_per_eu(2, 2)))
rnn_scan(const float* __restrict__ Wm, float* __restrict__ out_h) {
    __shared__ float part[2 * PARTSZ];   // 33280 B, only LDS in this kernel

    const int b = blockIdx.x;
    const int tid = threadIdx.x;
    const int w = tid >> 6, l = tid & 63;

    // ---- prologue: all weights -> registers; ch 0-5 pinned into AGPRs ----
    DECL8(0); DECL8(1); DECL8(2); DECL8(3); DECL8(4); DECL8(5); DECL8(6); DECL8(7);
    LOAD8(0); LOAD8(1); LOAD8(2); LOAD8(3); LOAD8(4); LOAD8(5); LOAD8(6); LOAD8(7);
    PINA8(0); PINA8(1); PINA8(2); PINA8(3); PINA8(4); PINA8(5);

    // h pairs, wave-uniform (SGPR): pair i = (h[64w+2i], h[64w+2i+1]), h0 = 0
    unsigned hp0 = 0, hp1 = 0, hp2 = 0, hp3 = 0, hp4 = 0, hp5 = 0, hp6 = 0, hp7 = 0,
             hp8 = 0, hp9 = 0, hp10 = 0, hp11 = 0, hp12 = 0, hp13 = 0, hp14 = 0,
             hp15 = 0, hp16 = 0, hp17 = 0, hp18 = 0, hp19 = 0, hp20 = 0, hp21 = 0,
             hp22 = 0, hp23 = 0, hp24 = 0, hp25 = 0, hp26 = 0, hp27 = 0, hp28 = 0,
             hp29 = 0, hp30 = 0, hp31 = 0;

    float* zh = out_h + (size_t)b * RNN_L + tid;      // Z in, h out (f32)
    float z = zh[0];
    const int c2 = tid & 7, l2 = tid >> 3;            // reduce: channel tid

#pragma unroll 1
    for (int t = 0; t < RNN_T; ++t) {
        const int tn = (t < RNN_T - 1) ? t + 1 : t;
        const float znext = zh[(size_t)tn * (RNN_B * RNN_L)];   // in flight
        float* pc = part + (t & 1) * PARTSZ;

        // ---- phase 1: partials for channels 8l+c over k in [64w,64w+64) ----
        float acc0 = 0.f, acc1 = 0.f, acc2 = 0.f, acc3 = 0.f;
        float acc4 = 0.f, acc5 = 0.f, acc6 = 0.f, acc7 = 0.f;
        DOTC(0); DOTC(1); DOTC(2); DOTC(3); DOTC(4); DOTC(5); DOTC(6); DOTC(7);

        pc[(0 * 8 + w) * 65 + l] = acc0;
        pc[(1 * 8 + w) * 65 + l] = acc1;
        pc[(2 * 8 + w) * 65 + l] = acc2;
        pc[(3 * 8 + w) * 65 + l] = acc3;
        pc[(4 * 8 + w) * 65 + l] = acc4;
        pc[(5 * 8 + w) * 65 + l] = acc5;
        pc[(6 * 8 + w) * 65 + l] = acc6;
        pc[(7 * 8 + w) * 65 + l] = acc7;

        __syncthreads();   // the ONLY barrier: partials visible; also orders
                           // next iteration's stores vs this one's reads

        // ---- phase 2: thread tid reduces channel tid (= 8*l2 + c2) ----
        float s = 0.f;
#pragma unroll
        for (int w2 = 0; w2 < 8; ++w2) s += pc[(c2 * 8 + w2) * 65 + l2];

        const float pre = z + s;
        const float hn = 1.f / (1.f + __expf(-pre));

        // h redistribution is INTRA-WAVE: pack pairs, broadcast via readlane
        const float hnb = __shfl_down(hn, 1);
        const unsigned pkh = pk2(hn, hnb);            // valid on even lanes
        RL(0);  RL(1);  RL(2);  RL(3);  RL(4);  RL(5);  RL(6);  RL(7);
        RL(8);  RL(9);  RL(10); RL(11); RL(12); RL(13); RL(14); RL(15);
        RL(16); RL(17); RL(18); RL(19); RL(20); RL(21); RL(22); RL(23);
        RL(24); RL(25); RL(26); RL(27); RL(28); RL(29); RL(30); RL(31);

        zh[(size_t)t * (RNN_B * RNN_L)] = hn;   // fire-and-forget
        z = znext;
    }
}

// ---------------------------------------------------------------------------
// K3: o[t,b] = sum_j Wo[j] * h[t,b,j]. Memory-bound re-read of h (~134 MB).
// ---------------------------------------------------------------------------
__global__ __launch_bounds__(256) void out_proj(
        const float* __restrict__ Wo, const float* __restrict__ h,
        float* __restrict__ o) {
    const int l = threadIdx.x & 63;
    const int r = blockIdx.x * 4 + (threadIdx.x >> 6);   // r = t*B + b
    const float4* hp = (const float4*)(h + (size_t)r * RNN_L);
    const float4* wp = (const float4*)Wo;
    float4 a0 = hp[l * 2], a1 = hp[l * 2 + 1];
    float4 b0 = wp[l * 2], b1 = wp[l * 2 + 1];
    float s = a0.x * b0.x + a0.y * b0.y + a0.z * b0.z + a0.w * b0.w
            + a1.x * b1.x + a1.y * b1.y + a1.z * b1.z + a1.w * b1.w;
#pragma unroll
    for (int off = 1; off < 64; off <<= 1) s += __shfl_xor(s, off);
    if (l == 0) o[r] = s;
}

// ---------------------------------------------------------------------------
extern "C" void kernel_launch(void* const* d_in, const int* in_sizes, int n_in,
                              void* d_out, int out_size, void* d_ws, size_t ws_size,
                              hipStream_t stream) {
    const float* x  = (const float*)d_in[0];   // [16,4096,256]
    const float* Wi = (const float*)d_in[1];   // [512,256]
    const float* Wm = (const float*)d_in[2];   // [512,512]
    const float* bm = (const float*)d_in[3];   // [512]
    const float* Wo = (const float*)d_in[4];   // [1,512]

    float* out_o = (float*)d_out;                 // [T*B] floats
    float* out_h = out_o + (RNN_T * RNN_B);       // [T*B*L] floats

    // K1: Z = x @ Wi^T + bm  -> hidden region (scratch, overwritten by K2)
    proj_kernel<<<dim3((RNN_T * RNN_B / 64) * (RNN_L / 64)), dim3(256), 0, stream>>>(
        x, Wi, bm, out_h);

    // K2: sequential recurrence (16 WGs, 33 KB static LDS, weights in V+A regs)
    rnn_scan<<<dim3(RNN_B), dim3(512), 0, stream>>>(Wm, out_h);

    // K3: o = h . Wo
    out_proj<<<dim3(RNN_T * RNN_B / 4), dim3(256), 0, stream>>>(Wo, out_h, out_o);
}

// Round 12
// 6988.109 us; speedup vs baseline: 4.0622x; 4.0622x over previous
//
#include <hip/hip_runtime.h>
#include <hip/hip_bf16.h>

// Problem constants (B,T,D,L) = (16, 4096, 256, 512)
#define RNN_B 16
#define RNN_T 4096
#define RNN_D 256
#define RNN_L 512

typedef __fp16   fp16x2 __attribute__((ext_vector_type(2)));  // builtin-compatible
typedef _Float16 f16x8  __attribute__((ext_vector_type(8)));  // MFMA fragment
typedef float    f32x4  __attribute__((ext_vector_type(4)));

__device__ __forceinline__ unsigned pk2(float a, float b) {
    auto h = __builtin_amdgcn_cvt_pkrtz(a, b);   // __fp16 ext_vector(2)
    return __builtin_bit_cast(unsigned, h);
}

__device__ __forceinline__ uint4 pk4(float4 a, float4 b) {
    uint4 u;
    u.x = pk2(a.x, a.y); u.y = pk2(a.z, a.w);
    u.z = pk2(b.x, b.y); u.w = pk2(b.z, b.w);
    return u;
}

__device__ __forceinline__ float dot2u(unsigned wa, unsigned hb, float c) {
#if defined(__has_builtin) && __has_builtin(__builtin_amdgcn_fdot2)
    return __builtin_amdgcn_fdot2(__builtin_bit_cast(fp16x2, wa),
                                  __builtin_bit_cast(fp16x2, hb), c, false);
#else
    fp16x2 a = __builtin_bit_cast(fp16x2, wa), b = __builtin_bit_cast(fp16x2, hb);
    return c + (float)a[0] * (float)b[0] + (float)a[1] * (float)b[1];
#endif
}

// ---------------------------------------------------------------------------
// K0: zero the flag region of the exchange scratch (must run EVERY launch;
// graph replay re-runs it before the scan -> monotonic flags start at 0).
// ---------------------------------------------------------------------------
__global__ __launch_bounds__(512) void init_flags(unsigned* __restrict__ ws) {
    ws[blockIdx.x * 512 + threadIdx.x] = 0u;     // 2 blocks x 512 = 1024 words
}

// ---------------------------------------------------------------------------
// K1: Z[t,b,l] = sum_k x[b,t,k] * Wi[l,k] + bm[l] (f32 into hidden region).
// ---------------------------------------------------------------------------
__global__ __launch_bounds__(256) void proj_kernel(
        const float* __restrict__ x, const float* __restrict__ Wi,
        const float* __restrict__ bm, float* __restrict__ Zout) {
    __shared__ __align__(16) _Float16 As[64 * 40];
    __shared__ __align__(16) _Float16 Bs[64 * 40];

    const int bid = blockIdx.x;
    const int mt = bid >> 3, nt = bid & 7;
    const int mBase = mt * 64, nBase = nt * 64;
    const int tid = threadIdx.x;
    const int w = tid >> 6, l = tid & 63;

    const int srow = tid >> 2, skc = (tid & 3) * 8;
    const int m = mBase + srow;
    const int bb = m & 15, tt = m >> 4;
    const float* ax = x + ((size_t)bb * RNN_T + tt) * RNN_D + skc;
    const float* bw = Wi + (size_t)(nBase + srow) * RNN_D + skc;

    f32x4 acc[4] = {};

#pragma unroll 1
    for (int k0 = 0; k0 < RNN_D; k0 += 32) {
        __syncthreads();
        float4 a0 = *(const float4*)(ax + k0);
        float4 a1 = *(const float4*)(ax + k0 + 4);
        float4 b0 = *(const float4*)(bw + k0);
        float4 b1 = *(const float4*)(bw + k0 + 4);
        uint4 ua = {pk2(a0.x, a0.y), pk2(a0.z, a0.w), pk2(a1.x, a1.y), pk2(a1.z, a1.w)};
        uint4 ub = {pk2(b0.x, b0.y), pk2(b0.z, b0.w), pk2(b1.x, b1.y), pk2(b1.z, b1.w)};
        *(uint4*)(As + srow * 40 + skc) = ua;
        *(uint4*)(Bs + srow * 40 + skc) = ub;
        __syncthreads();

        f16x8 af = *(const f16x8*)(As + (w * 16 + (l & 15)) * 40 + (l >> 4) * 8);
#pragma unroll
        for (int n = 0; n < 4; ++n) {
            f16x8 bf = *(const f16x8*)(Bs + (n * 16 + (l & 15)) * 40 + (l >> 4) * 8);
            acc[n] = __builtin_amdgcn_mfma_f32_16x16x32_f16(af, bf, acc[n], 0, 0, 0);
        }
    }

    const int colL = l & 15, rg = l >> 4;
#pragma unroll
    for (int n = 0; n < 4; ++n) {
        const int col = nBase + n * 16 + colL;
        const float bias = bm[col];
#pragma unroll
        for (int q = 0; q < 4; ++q) {
            const int row = mBase + w * 16 + rg * 4 + q;
            Zout[(size_t)row * RNN_L + col] = acc[n][q] + bias;
        }
    }
}

// ---------------------------------------------------------------------------
// K2: sequential scan, 4 CUs PER BATCH (64 blocks x 512 thr).
// R3-R11 closed the 16-CU budget: weights (512KB/CU/step) cannot flow without
// paying LDS (~8cyc/KB), AGPR move tax, or VMEM latency -> ~3400 cyc floor.
// At 4 CUs/batch each lane holds only 64 u32 of weights -> ALL in the 128-V
// budget, zero tax. Cross-CU h exchange via DEVICE-SCOPE ATOMICS (correct
// under XCD non-coherence; blocks {b,b+16,b+32,b+48} round-robin to one XCD):
//   producer: 64 atomicExch f16-pair slots -> __syncthreads (vmcnt drain)
//             -> one atomicExch flag[b][q] = t+1 (monotonic).
//   consumer wave w: spin flag[b][w>>1] >= t (lane0 atomicAdd+readfirstlane),
//             32 lanes atomic-read their k-window, readlane -> 32 SGPRs.
// Block (b = bid&15, q = bid>>4) owns channels [128q,128q+128); wave w owns
// k in [64w,64w+64); lane l computes channels 128q+2l, +1 (64 u32 weights).
// Cross-wave reduce via part[8][128]; h0=0 -> t=0 skips spin/load.
// ---------------------------------------------------------------------------
#define DOTG(g, h0_, h1_, h2_, h3_) do { \
    a0 = dot2u(A##g.x, h0_, a0); a0 = dot2u(A##g.y, h1_, a0); \
    a0 = dot2u(A##g.z, h2_, a0); a0 = dot2u(A##g.w, h3_, a0); \
    a1 = dot2u(B##g.x, h0_, a1); a1 = dot2u(B##g.y, h1_, a1); \
    a1 = dot2u(B##g.z, h2_, a1); a1 = dot2u(B##g.w, h3_, a1); } while (0)
#define HRL(i) const unsigned hp##i = (unsigned)__builtin_amdgcn_readlane((int)hv, i)

__global__ __launch_bounds__(512) void rnn_scan4(
        const float* __restrict__ Wm, float* __restrict__ out_h,
        unsigned* ws /* [1024] flags (64B-padded) + [2][16][256] slots */) {
    __shared__ float part[8 * 128];                  // 4 KB

    unsigned* flags = ws;                            // flag[(b*4+q)*16]
    unsigned* slots = ws + 1024;                     // [2][16][256]

    const int bid = blockIdx.x;
    const int b = bid & 15, q = bid >> 4;
    const int tid = threadIdx.x;
    const int w = tid >> 6, l = tid & 63;

    // ---- prologue: 2 channels x 8 uint4 weights -> named VGPRs (64 u32) ----
    const int ch0 = 128 * q + 2 * l;
    const float4* r0 = (const float4*)(Wm + (size_t)ch0 * RNN_L + 64 * w);
    const float4* r1 = (const float4*)(Wm + (size_t)(ch0 + 1) * RNN_L + 64 * w);
    uint4 A0 = pk4(r0[0],  r0[1]),  A1 = pk4(r0[2],  r0[3]);
    uint4 A2 = pk4(r0[4],  r0[5]),  A3 = pk4(r0[6],  r0[7]);
    uint4 A4 = pk4(r0[8],  r0[9]),  A5 = pk4(r0[10], r0[11]);
    uint4 A6 = pk4(r0[12], r0[13]), A7 = pk4(r0[14], r0[15]);
    uint4 B0 = pk4(r1[0],  r1[1]),  B1 = pk4(r1[2],  r1[3]);
    uint4 B2 = pk4(r1[4],  r1[5]),  B3 = pk4(r1[6],  r1[7]);
    uint4 B4 = pk4(r1[8],  r1[9]),  B5 = pk4(r1[10], r1[11]);
    uint4 B6 = pk4(r1[12], r1[13]), B7 = pk4(r1[14], r1[15]);

    // reduce-phase identity: thread handles global channel gch (4-fold dup)
    const int rch = tid >> 2, sub = tid & 3;         // rch 0..127
    const int gch = 128 * q + rch;
    float* zh = out_h + (size_t)b * RNN_L + gch;     // Z in, h out (f32)
    float z = zh[0];

    unsigned* fpost = &flags[((b << 2) | q) << 4];
    unsigned* fwait = &flags[((b << 2) | (w >> 1)) << 4];

#pragma unroll 1
    for (int t = 0; t < RNN_T; ++t) {
        const int tn = (t < RNN_T - 1) ? t + 1 : t;
        const float znext = zh[(size_t)tn * (RNN_B * RNN_L)];
        const int par = t & 1;

        // ---- acquire h[t]: spin producer flag, atomic-read k-window ----
        unsigned hv = 0;
        if (t > 0) {
            while (true) {
                unsigned fv = 0;
                if (l == 0) fv = atomicAdd(fwait, 0u);
                fv = (unsigned)__builtin_amdgcn_readfirstlane((int)fv);
                if ((int)fv >= t) break;
                __builtin_amdgcn_s_sleep(2);
            }
            if (l < 32)
                hv = atomicAdd(&slots[par * 4096 + b * 256 + 32 * w + l], 0u);
        }
        HRL(0);  HRL(1);  HRL(2);  HRL(3);  HRL(4);  HRL(5);  HRL(6);  HRL(7);
        HRL(8);  HRL(9);  HRL(10); HRL(11); HRL(12); HRL(13); HRL(14); HRL(15);
        HRL(16); HRL(17); HRL(18); HRL(19); HRL(20); HRL(21); HRL(22); HRL(23);
        HRL(24); HRL(25); HRL(26); HRL(27); HRL(28); HRL(29); HRL(30); HRL(31);

        // ---- partials over this wave's k-slice ----
        float a0 = 0.f, a1 = 0.f;
        DOTG(0, hp0,  hp1,  hp2,  hp3);   DOTG(1, hp4,  hp5,  hp6,  hp7);
        DOTG(2, hp8,  hp9,  hp10, hp11);  DOTG(3, hp12, hp13, hp14, hp15);
        DOTG(4, hp16, hp17, hp18, hp19);  DOTG(5, hp20, hp21, hp22, hp23);
        DOTG(6, hp24, hp25, hp26, hp27);  DOTG(7, hp28, hp29, hp30, hp31);

        *(float2*)&part[w * 128 + 2 * l] = make_float2(a0, a1);
        __syncthreads();                      // B1: partials visible

        // ---- reduce channel rch (4 threads/channel) ----
        float s = part[(2 * sub) * 128 + rch] + part[(2 * sub + 1) * 128 + rch];
        s += __shfl_xor(s, 1);
        s += __shfl_xor(s, 2);

        const float pre = z + s;
        const float hn = 1.f / (1.f + __expf(-pre));

        // ---- publish h[t+1]: f32 to output, f16-pairs to atomic slots ----
        const float hnb = __shfl_down(hn, 4);     // hn of channel rch+1
        if (sub == 0) {
            zh[(size_t)t * (RNN_B * RNN_L)] = hn;
            if (!(rch & 1))
                atomicExch(&slots[(par ^ 1) * 4096 + b * 256 + 64 * q + (rch >> 1)],
                           pk2(hn, hnb));
        }
        __syncthreads();                      // B2: vmcnt drain -> slots done
        if (tid == 0) atomicExch(fpost, (unsigned)(t + 1));
        z = znext;
    }
}

// ---------------------------------------------------------------------------
// K3: o[t,b] = sum_j Wo[j] * h[t,b,j]. Memory-bound re-read of h (~134 MB).
// Overwrites the out_o region (which held flags/slots scratch).
// ---------------------------------------------------------------------------
__global__ __launch_bounds__(256) void out_proj(
        const float* __restrict__ Wo, const float* __restrict__ h,
        float* __restrict__ o) {
    const int l = threadIdx.x & 63;
    const int r = blockIdx.x * 4 + (threadIdx.x >> 6);   // r = t*B + b
    const float4* hp = (const float4*)(h + (size_t)r * RNN_L);
    const float4* wp = (const float4*)Wo;
    float4 a0 = hp[l * 2], a1 = hp[l * 2 + 1];
    float4 b0 = wp[l * 2], b1 = wp[l * 2 + 1];
    float s = a0.x * b0.x + a0.y * b0.y + a0.z * b0.z + a0.w * b0.w
            + a1.x * b1.x + a1.y * b1.y + a1.z * b1.z + a1.w * b1.w;
#pragma unroll
    for (int off = 1; off < 64; off <<= 1) s += __shfl_xor(s, off);
    if (l == 0) o[r] = s;
}

// ---------------------------------------------------------------------------
extern "C" void kernel_launch(void* const* d_in, const int* in_sizes, int n_in,
                              void* d_out, int out_size, void* d_ws, size_t ws_size,
                              hipStream_t stream) {
    const float* x  = (const float*)d_in[0];   // [16,4096,256]
    const float* Wi = (const float*)d_in[1];   // [512,256]
    const float* Wm = (const float*)d_in[2];   // [512,512]
    const float* bm = (const float*)d_in[3];   // [512]
    const float* Wo = (const float*)d_in[4];   // [1,512]

    float* out_o = (float*)d_out;                 // [T*B] floats (256 KB)
    float* out_h = out_o + (RNN_T * RNN_B);       // [T*B*L] floats
    unsigned* xchg = (unsigned*)out_o;            // 36 KB scratch until K3

    // K0: zero the exchange flags (every launch; graph-replay safe)
    init_flags<<<dim3(2), dim3(512), 0, stream>>>(xchg);

    // K1: Z = x @ Wi^T + bm  -> hidden region (scratch, overwritten by K2)
    proj_kernel<<<dim3((RNN_T * RNN_B / 64) * (RNN_L / 64)), dim3(256), 0, stream>>>(
        x, Wi, bm, out_h);

    // K2: sequential recurrence, 4 blocks per batch, atomic h-exchange
    rnn_scan4<<<dim3(64), dim3(512), 0, stream>>>(Wm, out_h, xchg);

    // K3: o = h . Wo (overwrites the scratch region with real outputs)
    out_proj<<<dim3(RNN_T * RNN_B / 4), dim3(256), 0, stream>>>(Wo, out_h, out_o);
}

// Round 13
// 5224.528 us; speedup vs baseline: 5.4334x; 1.3376x over previous
//
#include <hip/hip_runtime.h>
#include <hip/hip_bf16.h>

// Problem constants (B,T,D,L) = (16, 4096, 256, 512)
#define RNN_B 16
#define RNN_T 4096
#define RNN_D 256
#define RNN_L 512

typedef __fp16   fp16x2 __attribute__((ext_vector_type(2)));  // builtin-compatible
typedef _Float16 f16x8  __attribute__((ext_vector_type(8)));  // MFMA fragment
typedef float    f32x4  __attribute__((ext_vector_type(4)));

__device__ __forceinline__ unsigned pk2(float a, float b) {
    auto h = __builtin_amdgcn_cvt_pkrtz(a, b);   // __fp16 ext_vector(2)
    return __builtin_bit_cast(unsigned, h);
}

__device__ __forceinline__ uint4 pk4(float4 a, float4 b) {
    uint4 u;
    u.x = pk2(a.x, a.y); u.y = pk2(a.z, a.w);
    u.z = pk2(b.x, b.y); u.w = pk2(b.z, b.w);
    return u;
}

__device__ __forceinline__ float dot2u(unsigned wa, unsigned hb, float c) {
#if defined(__has_builtin) && __has_builtin(__builtin_amdgcn_fdot2)
    return __builtin_amdgcn_fdot2(__builtin_bit_cast(fp16x2, wa),
                                  __builtin_bit_cast(fp16x2, hb), c, false);
#else
    fp16x2 a = __builtin_bit_cast(fp16x2, wa), b = __builtin_bit_cast(fp16x2, hb);
    return c + (float)a[0] * (float)b[0] + (float)a[1] * (float)b[1];
#endif
}

// ---------------------------------------------------------------------------
// K0: zero the exchange slots (EVERY launch; graph-replay safe: stale seq from
// a previous replay would otherwise satisfy polls). 8192 u64 = 16384 u32.
// ---------------------------------------------------------------------------
__global__ __launch_bounds__(512) void init_slots(unsigned* __restrict__ ws) {
    ws[blockIdx.x * 512 + threadIdx.x] = 0u;     // 32 blocks x 512
}

// ---------------------------------------------------------------------------
// K1: Z[t,b,l] = sum_k x[b,t,k] * Wi[l,k] + bm[l] (f32 into hidden region).
// ---------------------------------------------------------------------------
__global__ __launch_bounds__(256) void proj_kernel(
        const float* __restrict__ x, const float* __restrict__ Wi,
        const float* __restrict__ bm, float* __restrict__ Zout) {
    __shared__ __align__(16) _Float16 As[64 * 40];
    __shared__ __align__(16) _Float16 Bs[64 * 40];

    const int bid = blockIdx.x;
    const int mt = bid >> 3, nt = bid & 7;
    const int mBase = mt * 64, nBase = nt * 64;
    const int tid = threadIdx.x;
    const int w = tid >> 6, l = tid & 63;

    const int srow = tid >> 2, skc = (tid & 3) * 8;
    const int m = mBase + srow;
    const int bb = m & 15, tt = m >> 4;
    const float* ax = x + ((size_t)bb * RNN_T + tt) * RNN_D + skc;
    const float* bw = Wi + (size_t)(nBase + srow) * RNN_D + skc;

    f32x4 acc[4] = {};

#pragma unroll 1
    for (int k0 = 0; k0 < RNN_D; k0 += 32) {
        __syncthreads();
        float4 a0 = *(const float4*)(ax + k0);
        float4 a1 = *(const float4*)(ax + k0 + 4);
        float4 b0 = *(const float4*)(bw + k0);
        float4 b1 = *(const float4*)(bw + k0 + 4);
        uint4 ua = {pk2(a0.x, a0.y), pk2(a0.z, a0.w), pk2(a1.x, a1.y), pk2(a1.z, a1.w)};
        uint4 ub = {pk2(b0.x, b0.y), pk2(b0.z, b0.w), pk2(b1.x, b1.y), pk2(b1.z, b1.w)};
        *(uint4*)(As + srow * 40 + skc) = ua;
        *(uint4*)(Bs + srow * 40 + skc) = ub;
        __syncthreads();

        f16x8 af = *(const f16x8*)(As + (w * 16 + (l & 15)) * 40 + (l >> 4) * 8);
#pragma unroll
        for (int n = 0; n < 4; ++n) {
            f16x8 bf = *(const f16x8*)(Bs + (n * 16 + (l & 15)) * 40 + (l >> 4) * 8);
            acc[n] = __builtin_amdgcn_mfma_f32_16x16x32_f16(af, bf, acc[n], 0, 0, 0);
        }
    }

    const int colL = l & 15, rg = l >> 4;
#pragma unroll
    for (int n = 0; n < 4; ++n) {
        const int col = nBase + n * 16 + colL;
        const float bias = bm[col];
#pragma unroll
        for (int q = 0; q < 4; ++q) {
            const int row = mBase + w * 16 + rg * 4 + q;
            Zout[(size_t)row * RNN_L + col] = acc[n][q] + bias;
        }
    }
}

// ---------------------------------------------------------------------------
// K2: sequential scan, 4 CUs per batch (64 blocks x 512 thr) — R12 geometry
// (weights verifiably register-resident at VGPR=60) with a SINGLE-STAGE
// exchange: R12's step was 4030 cyc of which ~3200 was the two-RTT
// flag-then-data protocol. Now each 8-byte slot fuses {seq(hi32), h-pair
// f16x2(lo32)}: one relaxed agent-scope atomic store publishes; consumers
// poll their own word with plain agent loads — data validated by seq in the
// SAME word (one RTT stage, no RMW, no flags, no s_sleep, no B2 barrier).
// Safety: B1 sits between every poll(seq==t) and publish(seq=t+1), so a
// producer can never overwrite a parity buffer while any partner still polls
// it (publish(t+1) requires poll(t) of ALL waves; 2-parity buffering covers
// the rest). part[] double-buffered -> one barrier per step.
// Blocks {b,b+16,b+32,b+48} are same-XCD under round-robin (perf heuristic).
// ---------------------------------------------------------------------------
#define DOTG(g, h0_, h1_, h2_, h3_) do { \
    a0 = dot2u(A##g.x, h0_, a0); a0 = dot2u(A##g.y, h1_, a0); \
    a0 = dot2u(A##g.z, h2_, a0); a0 = dot2u(A##g.w, h3_, a0); \
    a1 = dot2u(B##g.x, h0_, a1); a1 = dot2u(B##g.y, h1_, a1); \
    a1 = dot2u(B##g.z, h2_, a1); a1 = dot2u(B##g.w, h3_, a1); } while (0)
#define HRL(i) const unsigned hp##i = (unsigned)__builtin_amdgcn_readlane((int)hv, i)

__global__ __launch_bounds__(512) void rnn_scan4(
        const float* __restrict__ Wm, float* __restrict__ out_h,
        unsigned long long* slots /* [2][16][256] u64: {seq, h-pair} */) {
    __shared__ float part[2][8 * 128];               // 8 KB, double-buffered

    const int bid = blockIdx.x;
    const int b = bid & 15, q = bid >> 4;
    const int tid = threadIdx.x;
    const int w = tid >> 6, l = tid & 63;

    // ---- prologue: 2 channels x 8 uint4 weights -> named VGPRs (64 u32) ----
    const int ch0 = 128 * q + 2 * l;
    const float4* r0 = (const float4*)(Wm + (size_t)ch0 * RNN_L + 64 * w);
    const float4* r1 = (const float4*)(Wm + (size_t)(ch0 + 1) * RNN_L + 64 * w);
    uint4 A0 = pk4(r0[0],  r0[1]),  A1 = pk4(r0[2],  r0[3]);
    uint4 A2 = pk4(r0[4],  r0[5]),  A3 = pk4(r0[6],  r0[7]);
    uint4 A4 = pk4(r0[8],  r0[9]),  A5 = pk4(r0[10], r0[11]);
    uint4 A6 = pk4(r0[12], r0[13]), A7 = pk4(r0[14], r0[15]);
    uint4 B0 = pk4(r1[0],  r1[1]),  B1 = pk4(r1[2],  r1[3]);
    uint4 B2 = pk4(r1[4],  r1[5]),  B3 = pk4(r1[6],  r1[7]);
    uint4 B4 = pk4(r1[8],  r1[9]),  B5 = pk4(r1[10], r1[11]);
    uint4 B6 = pk4(r1[12], r1[13]), B7 = pk4(r1[14], r1[15]);

    // reduce-phase identity: thread handles global channel gch (4-fold dup)
    const int rch = tid >> 2, sub = tid & 3;         // rch 0..127
    const int gch = 128 * q + rch;
    float* zh = out_h + (size_t)b * RNN_L + gch;     // Z in, h out (f32)
    float z = zh[0];

#pragma unroll 1
    for (int t = 0; t < RNN_T; ++t) {
        const int tn = (t < RNN_T - 1) ? t + 1 : t;
        const float znext = zh[(size_t)tn * (RNN_B * RNN_L)];   // overlaps spin

        // ---- acquire h[t]: poll own fused {seq,data} word (l < 32) ----
        unsigned hv = 0;
        if (t > 0) {
            unsigned long long* sp =
                slots + (size_t)(t & 1) * 4096 + b * 256 + 32 * w + l;
            bool rdy = (l >= 32);
            unsigned long long v = 0;
            while (!__all(rdy)) {
                if (!rdy) {
                    v = __hip_atomic_load(sp, __ATOMIC_RELAXED,
                                          __HIP_MEMORY_SCOPE_AGENT);
                    rdy = ((unsigned)(v >> 32) == (unsigned)t);
                }
            }
            hv = (unsigned)v;
        }
        HRL(0);  HRL(1);  HRL(2);  HRL(3);  HRL(4);  HRL(5);  HRL(6);  HRL(7);
        HRL(8);  HRL(9);  HRL(10); HRL(11); HRL(12); HRL(13); HRL(14); HRL(15);
        HRL(16); HRL(17); HRL(18); HRL(19); HRL(20); HRL(21); HRL(22); HRL(23);
        HRL(24); HRL(25); HRL(26); HRL(27); HRL(28); HRL(29); HRL(30); HRL(31);

        // ---- partials over this wave's k-slice ----
        float a0 = 0.f, a1 = 0.f;
        DOTG(0, hp0,  hp1,  hp2,  hp3);   DOTG(1, hp4,  hp5,  hp6,  hp7);
        DOTG(2, hp8,  hp9,  hp10, hp11);  DOTG(3, hp12, hp13, hp14, hp15);
        DOTG(4, hp16, hp17, hp18, hp19);  DOTG(5, hp20, hp21, hp22, hp23);
        DOTG(6, hp24, hp25, hp26, hp27);  DOTG(7, hp28, hp29, hp30, hp31);

        float* pc = part[t & 1];
        *(float2*)&pc[w * 128 + 2 * l] = make_float2(a0, a1);
        __syncthreads();      // B1: partials visible; also the protocol
                              // linchpin (all polls of seq t precede it,
                              // the publish of seq t+1 follows it)

        // ---- reduce channel rch (4 threads/channel) ----
        float s = pc[(2 * sub) * 128 + rch] + pc[(2 * sub + 1) * 128 + rch];
        s += __shfl_xor(s, 1);
        s += __shfl_xor(s, 2);

        const float pre = z + s;
        const float hn = 1.f / (1.f + __expf(-pre));

        // ---- publish h[t+1]: fused {seq=t+1, f16-pair} one-shot store ----
        const float hnb = __shfl_down(hn, 4);        // hn of channel rch+1
        if (sub == 0) {
            if (!(rch & 1)) {
                const unsigned long long pv =
                    (unsigned long long)pk2(hn, hnb) |
                    ((unsigned long long)(unsigned)(t + 1) << 32);
                __hip_atomic_store(
                    &slots[(size_t)((t + 1) & 1) * 4096 + b * 256 + 64 * q + (rch >> 1)],
                    pv, __ATOMIC_RELAXED, __HIP_MEMORY_SCOPE_AGENT);
            }
            zh[(size_t)t * (RNN_B * RNN_L)] = hn;    // fire-and-forget
        }
        z = znext;
    }
}

// ---------------------------------------------------------------------------
// K3: o[t,b] = sum_j Wo[j] * h[t,b,j]. Memory-bound re-read of h (~134 MB).
// Overwrites the out_o region (which held the exchange slots).
// ---------------------------------------------------------------------------
__global__ __launch_bounds__(256) void out_proj(
        const float* __restrict__ Wo, const float* __restrict__ h,
        float* __restrict__ o) {
    const int l = threadIdx.x & 63;
    const int r = blockIdx.x * 4 + (threadIdx.x >> 6);   // r = t*B + b
    const float4* hp = (const float4*)(h + (size_t)r * RNN_L);
    const float4* wp = (const float4*)Wo;
    float4 a0 = hp[l * 2], a1 = hp[l * 2 + 1];
    float4 b0 = wp[l * 2], b1 = wp[l * 2 + 1];
    float s = a0.x * b0.x + a0.y * b0.y + a0.z * b0.z + a0.w * b0.w
            + a1.x * b1.x + a1.y * b1.y + a1.z * b1.z + a1.w * b1.w;
#pragma unroll
    for (int off = 1; off < 64; off <<= 1) s += __shfl_xor(s, off);
    if (l == 0) o[r] = s;
}

// ---------------------------------------------------------------------------
extern "C" void kernel_launch(void* const* d_in, const int* in_sizes, int n_in,
                              void* d_out, int out_size, void* d_ws, size_t ws_size,
                              hipStream_t stream) {
    const float* x  = (const float*)d_in[0];   // [16,4096,256]
    const float* Wi = (const float*)d_in[1];   // [512,256]
    const float* Wm = (const float*)d_in[2];   // [512,512]
    const float* bm = (const float*)d_in[3];   // [512]
    const float* Wo = (const float*)d_in[4];   // [1,512]

    float* out_o = (float*)d_out;                 // [T*B] floats (256 KB)
    float* out_h = out_o + (RNN_T * RNN_B);       // [T*B*L] floats
    unsigned long long* slots = (unsigned long long*)out_o;   // 64 KB scratch

    // K0: zero the fused exchange slots (every launch; graph-replay safe)
    init_slots<<<dim3(32), dim3(512), 0, stream>>>((unsigned*)slots);

    // K1: Z = x @ Wi^T + bm  -> hidden region (scratch, overwritten by K2)
    proj_kernel<<<dim3((RNN_T * RNN_B / 64) * (RNN_L / 64)), dim3(256), 0, stream>>>(
        x, Wi, bm, out_h);

    // K2: sequential recurrence, 4 blocks/batch, single-stage fused exchange
    rnn_scan4<<<dim3(64), dim3(512), 0, stream>>>(Wm, out_h, slots);

    // K3: o = h . Wo (overwrites the scratch region with real outputs)
    out_proj<<<dim3(RNN_T * RNN_B / 4), dim3(256), 0, stream>>>(Wo, out_h, out_o);
}